// Round 1
// baseline (134.392 us; speedup 1.0000x reference)
//
#include <hip/hip_runtime.h>

// Batched matmul: [24,1024,64] fp32 x [24,64,1024] fp32 -> [24,1024,1024] fp32.
// R7: FUSED single kernel. The reformat pass + 6.3MB workspace round-trip is
// pure overhead: each lane can gather its MFMA fragments directly from the
// fp32 operands (A: 8 contiguous floats = 2x float4; B: 8 stride-4KB scalars,
// coalesced across lanes). Inputs are 12.6MB -> fully L2/L3 resident, so the
// 8x block-level re-read is cache-served and hidden under the 100MB store
// stream. GEMM core + epilogue byte-identical in math to the verified R3/R6
// path (same f2bs RNE, same fragment contents, same ks order) -> same absmax.

#define NN 1024

typedef __attribute__((ext_vector_type(4))) float  float4v;
typedef __attribute__((ext_vector_type(8))) short  bf16x8;    // 8 bf16 = 16 B
typedef __attribute__((ext_vector_type(16))) float floatx16;  // 32x32 MFMA acc

// fp32 -> bf16 bits, round-to-nearest-even (inputs finite)
__device__ __forceinline__ short f2bs(float f) {
    union { float f; unsigned u; } in;
    in.f = f;
    unsigned u = in.u;
    return (short)((u + 0x7FFFu + ((u >> 16) & 1u)) >> 16);
}

// Fragment layout (32x32x16 bf16; verified end-to-end R1-R3):
//   element (idx, k): ks = k>>4, q = (k>>3)&1, j = k&7
//   lane = (idx&31) + q*32, frag short j holds k = ks*16 + q*8 + j
// A indexed by m over [m][k] row-major; B indexed by n over [k][n].
// Non-swapped mfma(a,b,acc): col = lane&31 -> n (contiguous across lanes),
// row = (r&3)+8*(r>>2)+4*(lane>>5) -> m. Each scalar nt store instr covers
// exactly 2 full 128-B lines of the 100MB output stream.
__global__ __launch_bounds__(256, 4) void bmm_fused(const float* __restrict__ A,
                                                    const float* __restrict__ B,
                                                    float* __restrict__ C) {
    const int tid  = threadIdx.x;
    const int lane = tid & 63;
    const int w    = tid >> 6;
    const int bx = blockIdx.x;   // n-tile128 0..7
    const int by = blockIdx.y;   // m-tile128 0..7
    const int bh = blockIdx.z;   // 0..23
    const int wm = (w >> 1) * 2; // 32-tile base in m within the 128 tile
    const int wn = (w & 1) * 2;
    const int l31 = lane & 31;
    const int q   = lane >> 5;

    // A: lane reads rows (by*128 + (wm+mi)*32 + l31), k = ks*16 + q*8 + j
    const float* Ab = A + ((size_t)bh << 16)
                        + (size_t)(by * 128 + wm * 32 + l31) * 64 + q * 8;
    // B: lane reads col (bx*128 + (wn+ni)*32 + l31), k = ks*16 + q*8 + j
    const float* Bb = B + ((size_t)bh << 16)
                        + (size_t)(q * 8) * NN + (bx * 128 + wn * 32 + l31);

    floatx16 acc[2][2];
    #pragma unroll
    for (int mi = 0; mi < 2; ++mi)
        #pragma unroll
        for (int ni = 0; ni < 2; ++ni)
            #pragma unroll
            for (int r = 0; r < 16; ++r)
                acc[mi][ni][r] = 0.0f;

    #pragma unroll
    for (int ks = 0; ks < 4; ++ks) {
        // ---- A fragments: 8 contiguous fp32 per lane per tile ----
        const float* pa0 = Ab + ks * 16;
        const float* pa1 = pa0 + 32 * 64;          // next 32-row m-tile
        float4v a0lo = *(const float4v*)(pa0);
        float4v a0hi = *(const float4v*)(pa0 + 4);
        float4v a1lo = *(const float4v*)(pa1);
        float4v a1hi = *(const float4v*)(pa1 + 4);

        // ---- B fragments: 8 stride-4KB scalars per lane per tile ----
        const float* pb = Bb + (size_t)(ks * 16) * NN;
        float b0f[8], b1f[8];
        #pragma unroll
        for (int j = 0; j < 8; ++j) {
            b0f[j] = pb[(size_t)j * NN];
            b1f[j] = pb[(size_t)j * NN + 32];      // next 32-col n-tile
        }

        bf16x8 a0, a1, b0, b1;
        a0[0] = f2bs(a0lo.x); a0[1] = f2bs(a0lo.y); a0[2] = f2bs(a0lo.z); a0[3] = f2bs(a0lo.w);
        a0[4] = f2bs(a0hi.x); a0[5] = f2bs(a0hi.y); a0[6] = f2bs(a0hi.z); a0[7] = f2bs(a0hi.w);
        a1[0] = f2bs(a1lo.x); a1[1] = f2bs(a1lo.y); a1[2] = f2bs(a1lo.z); a1[3] = f2bs(a1lo.w);
        a1[4] = f2bs(a1hi.x); a1[5] = f2bs(a1hi.y); a1[6] = f2bs(a1hi.z); a1[7] = f2bs(a1hi.w);
        #pragma unroll
        for (int j = 0; j < 8; ++j) {
            b0[j] = f2bs(b0f[j]);
            b1[j] = f2bs(b1f[j]);
        }

        acc[0][0] = __builtin_amdgcn_mfma_f32_32x32x16_bf16(a0, b0, acc[0][0], 0, 0, 0);
        acc[0][1] = __builtin_amdgcn_mfma_f32_32x32x16_bf16(a0, b1, acc[0][1], 0, 0, 0);
        acc[1][0] = __builtin_amdgcn_mfma_f32_32x32x16_bf16(a1, b0, acc[1][0], 0, 0, 0);
        acc[1][1] = __builtin_amdgcn_mfma_f32_32x32x16_bf16(a1, b1, acc[1][1], 0, 0, 0);
    }

    // Epilogue: identical to verified R3/R6. Non-temporal scalar stores;
    // each store instruction covers 2 full 128-B lines.
    const int nc    = l31;       // n within 32-tile (contiguous across lanes)
    const int rbase = q * 4;     // m sub-base
    float* Cb = C + ((size_t)bh << 20)
                  + (size_t)(by * 128 + wm * 32) * NN
                  + bx * 128 + wn * 32 + nc;

    #pragma unroll
    for (int mi = 0; mi < 2; ++mi) {
        #pragma unroll
        for (int ni = 0; ni < 2; ++ni) {
            float* Ct = Cb + (size_t)(mi * 32) * NN + ni * 32;
            #pragma unroll
            for (int r = 0; r < 16; ++r) {
                int row = rbase + (r & 3) + ((r >> 2) * 8);
                __builtin_nontemporal_store(acc[mi][ni][r], Ct + (size_t)row * NN);
            }
        }
    }
}

extern "C" void kernel_launch(void* const* d_in, const int* in_sizes, int n_in,
                              void* d_out, int out_size, void* d_ws, size_t ws_size,
                              hipStream_t stream) {
    const float* x1 = (const float*)d_in[0];   // [2,12,1024,64]
    const float* x2 = (const float*)d_in[1];   // [2,12,64,1024]
    float* out = (float*)d_out;                // [2,12,1024,1024] fp32

    (void)d_ws; (void)ws_size;                 // workspace no longer needed

    hipLaunchKernelGGL(bmm_fused, dim3(8, 8, 24), dim3(256), 0, stream, x1, x2, out);
}

// Round 3
// 121.655 us; speedup vs baseline: 1.1047x; 1.1047x over previous
//
#include <hip/hip_runtime.h>
#include <hip/hip_bf16.h>

// Batched matmul: [24,1024,64] fp32 x [24,64,1024] fp32 -> [24,1024,1024] fp32.
// R8 = R6 structure (verified 122.2us) with ONE change: the bmm epilogue's
// output stores are PLAIN cached stores instead of __builtin_nontemporal_store.
// Single-variable A/B: the only observed 6.5TB/s write streams on this chip
// (harness fill, m13 ubench) use the normal L2-allocating write path; nt may
// force a slower TCC write mode. Everything else is byte-identical to R6.
// (Round-2 resubmit: previous bench died on container acquisition, not kernel.)

#define NN 1024

typedef __attribute__((ext_vector_type(4))) float  float4v;
typedef __attribute__((ext_vector_type(8))) short  bf16x8;    // 8 bf16 = 16 B
typedef __attribute__((ext_vector_type(16))) float floatx16;  // 32x32 MFMA acc

// fp32 -> bf16 bits, round-to-nearest-even (inputs finite)
__device__ __forceinline__ short f2bs(float f) {
    union { float f; unsigned u; } in;
    in.f = f;
    unsigned u = in.u;
    return (short)((u + 0x7FFFu + ((u >> 16) & 1u)) >> 16);
}

// Fragment layout (32x32x16 bf16; verified end-to-end R1-R3):
//   element (idx, k): tile = idx>>5, ks = k>>4, q = (k>>3)&1, j = k&7
//   lane = (idx&31) + q*32, short addr = ((bh*32+tile)*4 + ks)*512 + lane*8 + j
// A indexed by m over [m][k] row-major; B indexed by n over [k][n].

// Reformat: blocks 0..767 handle A (one task/thread), 768..1535 handle B.
__global__ __launch_bounds__(256) void reformat_AB(const float* __restrict__ A,
                                                   const float* __restrict__ B,
                                                   short* __restrict__ Aw,
                                                   short* __restrict__ Bw) {
    const int bid = blockIdx.x;
    if (bid < 768) {
        int task = bid * 256 + threadIdx.x;      // 0..196607  [bh][m][kg]
        int bh   = task >> 13;
        int rem  = task & 8191;
        int m    = rem >> 3;
        int kg   = rem & 7;
        const float4v* p = (const float4v*)(A + (size_t)task * 8);
        float4v v0 = __builtin_nontemporal_load(p);
        float4v v1 = __builtin_nontemporal_load(p + 1);
        int ks = kg >> 1, q = kg & 1;
        int mt = m >> 5;
        int lane = (m & 31) + (q << 5);
        size_t dst = ((size_t)((bh * 32 + mt) * 4 + ks)) * 512 + (size_t)lane * 8;
        bf16x8 o;
        o[0] = f2bs(v0.x); o[1] = f2bs(v0.y); o[2] = f2bs(v0.z); o[3] = f2bs(v0.w);
        o[4] = f2bs(v1.x); o[5] = f2bs(v1.y); o[6] = f2bs(v1.z); o[7] = f2bs(v1.w);
        *(bf16x8*)(Aw + dst) = o;
    } else {
        int task = (bid - 768) * 256 + threadIdx.x;  // 0..196607  [kg][bh][n]
        int kg   = task / 24576;                 // 0..7
        int rem  = task - kg * 24576;
        int bh   = rem >> 10;
        int n    = rem & 1023;
        const float* p = B + (size_t)bh * 65536 + (size_t)kg * 8192 + n;
        float v0 = __builtin_nontemporal_load(p + 0 * 1024);
        float v1 = __builtin_nontemporal_load(p + 1 * 1024);
        float v2 = __builtin_nontemporal_load(p + 2 * 1024);
        float v3 = __builtin_nontemporal_load(p + 3 * 1024);
        float v4 = __builtin_nontemporal_load(p + 4 * 1024);
        float v5 = __builtin_nontemporal_load(p + 5 * 1024);
        float v6 = __builtin_nontemporal_load(p + 6 * 1024);
        float v7 = __builtin_nontemporal_load(p + 7 * 1024);
        int ks = kg >> 1, q = kg & 1;
        int nt = n >> 5;
        int lane = (n & 31) + (q << 5);
        size_t dst = ((size_t)((bh * 32 + nt) * 4 + ks)) * 512 + (size_t)lane * 8;
        bf16x8 o;
        o[0] = f2bs(v0); o[1] = f2bs(v1); o[2] = f2bs(v2); o[3] = f2bs(v3);
        o[4] = f2bs(v4); o[5] = f2bs(v5); o[6] = f2bs(v6); o[7] = f2bs(v7);
        *(bf16x8*)(Bw + dst) = o;
    }
}

// GEMM: no LDS, no syncthreads. Each wave: 64x64 output (2x2 of 32x32).
// Non-swapped mfma(a,b,acc): col = lane&31 -> n (contiguous across lanes),
// row = (r&3)+8*(r>>2)+4*(lane>>5) -> m. Each scalar store instr covers
// exactly 2 full 128-B lines. R8: plain cached stores (nt removed).
__global__ __launch_bounds__(256) void bmm_frag(const short* __restrict__ Aw,
                                                const short* __restrict__ Bw,
                                                float* __restrict__ C) {
    const int tid  = threadIdx.x;
    const int lane = tid & 63;
    const int w    = tid >> 6;
    const int bx = blockIdx.x;   // n-tile128 0..7
    const int by = blockIdx.y;   // m-tile128 0..7
    const int bh = blockIdx.z;   // 0..23
    const int wm = (w >> 1) * 2; // 32-tile base in m within the 128 tile
    const int wn = (w & 1) * 2;

    const short* Ab = Aw + ((size_t)((bh * 32 + by * 4 + wm) * 4)) * 512 + (size_t)lane * 8;
    const short* Bb = Bw + ((size_t)((bh * 32 + bx * 4 + wn) * 4)) * 512 + (size_t)lane * 8;
    // next 32-tile: +2048 shorts; next ks: +512 shorts

    floatx16 acc[2][2];
    #pragma unroll
    for (int mi = 0; mi < 2; ++mi)
        #pragma unroll
        for (int ni = 0; ni < 2; ++ni)
            #pragma unroll
            for (int r = 0; r < 16; ++r)
                acc[mi][ni][r] = 0.0f;

    #pragma unroll
    for (int ks = 0; ks < 4; ++ks) {
        bf16x8 a0 = *(const bf16x8*)(Ab + ks * 512);
        bf16x8 a1 = *(const bf16x8*)(Ab + 2048 + ks * 512);
        bf16x8 b0 = *(const bf16x8*)(Bb + ks * 512);
        bf16x8 b1 = *(const bf16x8*)(Bb + 2048 + ks * 512);
        acc[0][0] = __builtin_amdgcn_mfma_f32_32x32x16_bf16(a0, b0, acc[0][0], 0, 0, 0);
        acc[0][1] = __builtin_amdgcn_mfma_f32_32x32x16_bf16(a0, b1, acc[0][1], 0, 0, 0);
        acc[1][0] = __builtin_amdgcn_mfma_f32_32x32x16_bf16(a1, b0, acc[1][0], 0, 0, 0);
        acc[1][1] = __builtin_amdgcn_mfma_f32_32x32x16_bf16(a1, b1, acc[1][1], 0, 0, 0);
    }

    const int nc    = lane & 31;        // n within 32-tile (contiguous across lanes)
    const int rbase = (lane >> 5) * 4;  // m sub-base
    float* Cb = C + ((size_t)bh << 20)
                  + (size_t)(by * 128 + wm * 32) * NN
                  + bx * 128 + wn * 32 + nc;

    #pragma unroll
    for (int mi = 0; mi < 2; ++mi) {
        #pragma unroll
        for (int ni = 0; ni < 2; ++ni) {
            float* Ct = Cb + (size_t)(mi * 32) * NN + ni * 32;
            #pragma unroll
            for (int r = 0; r < 16; ++r) {
                int row = rbase + (r & 3) + ((r >> 2) * 8);
                Ct[(size_t)row * NN] = acc[mi][ni][r];
            }
        }
    }
}

extern "C" void kernel_launch(void* const* d_in, const int* in_sizes, int n_in,
                              void* d_out, int out_size, void* d_ws, size_t ws_size,
                              hipStream_t stream) {
    const float* x1 = (const float*)d_in[0];   // [2,12,1024,64]
    const float* x2 = (const float*)d_in[1];   // [2,12,64,1024]
    float* out = (float*)d_out;                // [2,12,1024,1024] fp32

    short* Aw = (short*)d_ws;                  // 1,572,864 bf16 = 3.1 MB
    short* Bw = Aw + 1572864;                  // 3.1 MB

    hipLaunchKernelGGL(reformat_AB, dim3(1536), dim3(256), 0, stream, x1, x2, Aw, Bw);
    hipLaunchKernelGGL(bmm_frag, dim3(8, 8, 24), dim3(256), 0, stream, Aw, Bw, out);
}